// Round 5
// baseline (172.089 us; speedup 1.0000x reference)
//
#include <hip/hip_runtime.h>
#include <hip/hip_bf16.h>

#define TT 256   // sequence length
#define CE 384   // embed
#define HD 64    // head size

typedef __attribute__((ext_vector_type(8))) short short8v;
typedef __attribute__((ext_vector_type(4))) float float4v;
typedef __attribute__((ext_vector_type(4))) unsigned int uint4v;
typedef __attribute__((ext_vector_type(4))) unsigned short ushort4v;

#define SCALE 0.05103103630798287f  // 384^-0.5 (reference scales by C, not H)

__device__ __forceinline__ unsigned short f2bf(float f) {
    union { __hip_bfloat16 b; unsigned short u; } cv;
    cv.b = __float2bfloat16(f);   // RNE; pairs fuse to v_cvt_pk_bf16_f32
    return cv.u;
}
__device__ __forceinline__ unsigned int pk2(float a, float b) {
    return (unsigned int)f2bf(a) | ((unsigned int)f2bf(b) << 16);
}

// Swizzled LDS addressing (16B-chunk XOR of row bits -> conflict-free frag reads)
__device__ __forceinline__ int adr8(int row, int col) {   // rows of 64 bf16 (128 B)
    return row * 128 + ((((col >> 3) ^ (row & 7)) & 7) << 4) + ((col & 7) << 1);
}
__device__ __forceinline__ int adr32(int row, int col) {  // rows of 256 bf16 (512 B)
    return row * 512 + ((((col >> 3) ^ (row & 31)) & 31) << 4) + ((col & 7) << 1);
}

// raw barrier: drain LDS ops only -- global prefetch loads stay in flight
#define BAR() do {                                            \
    asm volatile("s_waitcnt lgkmcnt(0)" ::: "memory");        \
    __builtin_amdgcn_s_barrier();                             \
    __builtin_amdgcn_sched_barrier(0);                        \
} while (0)

// ---------------- kernel 0: weight transpose + bf16 convert -----------------
__global__ void wprep(const float* __restrict__ Wk, const float* __restrict__ Wq,
                      const float* __restrict__ Wv, unsigned short* __restrict__ Wt) {
    int idx = blockIdx.x * 256 + threadIdx.x;
    if (idx >= 3 * HD * CE) return;
    int w = idx / (HD * CE);
    int rem = idx - w * (HD * CE);
    int h = rem / CE;
    int c = rem - h * CE;
    const float* W = (w == 0) ? Wk : (w == 1) ? Wq : Wv;
    Wt[idx] = f2bf(W[c * HD + h]);
}

// ---------------- fused persistent kernel: 2 batches per block --------------
// 1024 threads (16 waves), grid 256 -> 1 block/CU, batches b and b+256.
// LDS (160 KiB), time-shared:
//   Vts @ 0      : 32 KiB  [64][256] bf16 (adr32)  V transposed
//   Qs  @ 32768  : 32 KiB  [256][64] bf16 (adr8)   \  dead after QK^T
//   Ks  @ 65536  : 32 KiB  [256][64] bf16 (adr8)   /
//   Xs  @ 98304  : 32 KiB  phase-1 X staging        \ dead after phase 1
//   Ws  @ 131072 : 24 KiB  phase-1 W staging        /
//   Wts @ 32768  : 128 KiB [256][256] bf16 (adr32) softmax weights
//                  (overlaps Qs/Ks/Xs/Ws -- written after QK^T, read by PV)
__global__ __launch_bounds__(1024, 4)
void fused(const float* __restrict__ X, const unsigned short* __restrict__ Wt,
           float* __restrict__ out) {
    extern __shared__ char lds[];
    char* Vts = lds;
    char* Qs  = lds + 32768;
    char* Ks  = lds + 65536;
    char* Xs  = lds + 98304;
    char* Ws  = lds + 131072;
    char* Wts = lds + 32768;

    const int tid = threadIdx.x;
    const int w = tid >> 6, l = tid & 63;
    const int l15 = l & 15, lq = l >> 4;
    const int tg = w & 7, nh = w >> 3;      // phase-1 wave role

    // staging slots: X 2048 chunks / 1024 thr = 2; W 1536 / 1024 = 1.5 (slot1: tid<512)
    const int xt0 = tid >> 3,        xk0 = tid & 7;
    const int xt1 = 128 + (tid >> 3), xk1 = tid & 7;
    const int wn0 = tid >> 3,        wk0 = tid & 7;
    const int wn1 = 128 + (tid >> 3), wk1 = tid & 7;
    const bool wp = (tid < 512);

    // named 2-deep register double-buffer (rule #20: no runtime indexing)
    float4 xrA[2][2]; uint4v wrA[2];
    float4 xrB[2][2]; uint4v wrB[2];

    auto issueA = [&](const float* xb, int kk) {
        const float* s0 = xb + xt0 * CE + kk + xk0 * 8;
        xrA[0][0] = *(const float4*)s0;  xrA[0][1] = *(const float4*)(s0 + 4);
        const float* s1 = xb + xt1 * CE + kk + xk1 * 8;
        xrA[1][0] = *(const float4*)s1;  xrA[1][1] = *(const float4*)(s1 + 4);
        wrA[0] = *(const uint4v*)(Wt + wn0 * CE + kk + wk0 * 8);
        if (wp) wrA[1] = *(const uint4v*)(Wt + wn1 * CE + kk + wk1 * 8);
    };
    auto issueB = [&](const float* xb, int kk) {
        const float* s0 = xb + xt0 * CE + kk + xk0 * 8;
        xrB[0][0] = *(const float4*)s0;  xrB[0][1] = *(const float4*)(s0 + 4);
        const float* s1 = xb + xt1 * CE + kk + xk1 * 8;
        xrB[1][0] = *(const float4*)s1;  xrB[1][1] = *(const float4*)(s1 + 4);
        wrB[0] = *(const uint4v*)(Wt + wn0 * CE + kk + wk0 * 8);
        if (wp) wrB[1] = *(const uint4v*)(Wt + wn1 * CE + kk + wk1 * 8);
    };
    auto storeA = [&]() {
        uint4v p0 = {pk2(xrA[0][0].x, xrA[0][0].y), pk2(xrA[0][0].z, xrA[0][0].w),
                     pk2(xrA[0][1].x, xrA[0][1].y), pk2(xrA[0][1].z, xrA[0][1].w)};
        *(uint4v*)(Xs + xt0 * 128 + (((xk0 ^ (xt0 & 7)) & 7) << 4)) = p0;
        uint4v p1 = {pk2(xrA[1][0].x, xrA[1][0].y), pk2(xrA[1][0].z, xrA[1][0].w),
                     pk2(xrA[1][1].x, xrA[1][1].y), pk2(xrA[1][1].z, xrA[1][1].w)};
        *(uint4v*)(Xs + xt1 * 128 + (((xk1 ^ (xt1 & 7)) & 7) << 4)) = p1;
        *(uint4v*)(Ws + wn0 * 128 + (((wk0 ^ (wn0 & 7)) & 7) << 4)) = wrA[0];
        if (wp) *(uint4v*)(Ws + wn1 * 128 + (((wk1 ^ (wn1 & 7)) & 7) << 4)) = wrA[1];
    };
    auto storeB = [&]() {
        uint4v p0 = {pk2(xrB[0][0].x, xrB[0][0].y), pk2(xrB[0][0].z, xrB[0][0].w),
                     pk2(xrB[0][1].x, xrB[0][1].y), pk2(xrB[0][1].z, xrB[0][1].w)};
        *(uint4v*)(Xs + xt0 * 128 + (((xk0 ^ (xt0 & 7)) & 7) << 4)) = p0;
        uint4v p1 = {pk2(xrB[1][0].x, xrB[1][0].y), pk2(xrB[1][0].z, xrB[1][0].w),
                     pk2(xrB[1][1].x, xrB[1][1].y), pk2(xrB[1][1].z, xrB[1][1].w)};
        *(uint4v*)(Xs + xt1 * 128 + (((xk1 ^ (xt1 & 7)) & 7) << 4)) = p1;
        *(uint4v*)(Ws + wn0 * 128 + (((wk0 ^ (wn0 & 7)) & 7) << 4)) = wrB[0];
        if (wp) *(uint4v*)(Ws + wn1 * 128 + (((wk1 ^ (wn1 & 7)) & 7) << 4)) = wrB[1];
    };

    const float4v fzero = {0.f, 0.f, 0.f, 0.f};
    float4v acc[2][6];

    auto mfma_phase = [&]() {
        #pragma unroll
        for (int ks = 0; ks < 2; ++ks) {
            short8v a0 = *(const short8v*)(Xs + adr8(tg * 32 + l15,      ks * 32 + lq * 8));
            short8v a1 = *(const short8v*)(Xs + adr8(tg * 32 + 16 + l15, ks * 32 + lq * 8));
            #pragma unroll
            for (int nt = 0; nt < 6; ++nt) {
                short8v bb = *(const short8v*)(Ws + adr8(nh * 96 + nt * 16 + l15, ks * 32 + lq * 8));
                acc[0][nt] = __builtin_amdgcn_mfma_f32_16x16x32_bf16(a0, bb, acc[0][nt], 0, 0, 0);
                acc[1][nt] = __builtin_amdgcn_mfma_f32_16x16x32_bf16(a1, bb, acc[1][nt], 0, 0, 0);
            }
        }
    };

    const int b0 = blockIdx.x;
    issueA(X + (long)b0 * TT * CE, 0);
    issueB(X + (long)b0 * TT * CE, 64);

    #pragma unroll
    for (int bb = 0; bb < 2; ++bb) {
        const int bat = b0 + bb * 256;
        const float* Xb = X + (long)bat * TT * CE;

        #pragma unroll
        for (int i = 0; i < 2; ++i)
            #pragma unroll
            for (int j = 0; j < 6; ++j) acc[i][j] = fzero;

        // ---------------- phase 1: QKV GEMM, 6 K-chunks, A/B pipelined ------
        #pragma unroll
        for (int kc2 = 0; kc2 < 3; ++kc2) {
            storeA();
            if (kc2 < 2) issueA(Xb, (2 * kc2 + 2) * 64);
            BAR();                       // ds_writes visible; global loads in flight
            mfma_phase();
            BAR();                       // frag reads landed; scratch free
            storeB();
            if (kc2 < 2) issueB(Xb, (2 * kc2 + 3) * 64);
            BAR();
            mfma_phase();
            BAR();
        }

        // epilogue: K,Q -> Ks/Qs (adr8); V -> Vts transposed [h][s] (adr32)
        #pragma unroll
        for (int rt = 0; rt < 2; ++rt) {
            const int t0 = tg * 32 + rt * 16 + lq * 4;
            #pragma unroll
            for (int nt = 0; nt < 6; ++nt) {
                const int n = nh * 96 + nt * 16 + l15;
                if (n < 64) {              // K
                    #pragma unroll
                    for (int r = 0; r < 4; ++r)
                        *(unsigned short*)(Ks + adr8(t0 + r, n)) = f2bf(acc[rt][nt][r]);
                } else if (n < 128) {      // Q
                    const int h = n - 64;
                    #pragma unroll
                    for (int r = 0; r < 4; ++r)
                        *(unsigned short*)(Qs + adr8(t0 + r, h)) = f2bf(acc[rt][nt][r]);
                } else {                   // V -> [h][s]
                    const int h = n - 128;
                    ushort4v pv;
                    pv[0] = f2bf(acc[rt][nt][0]);
                    pv[1] = f2bf(acc[rt][nt][1]);
                    pv[2] = f2bf(acc[rt][nt][2]);
                    pv[3] = f2bf(acc[rt][nt][3]);
                    *(ushort4v*)(Vts + adr32(h, t0)) = pv;
                }
            }
        }
        BAR();   // K/Q/V slabs ready

        // ---------------- phase 2: one-shot attention ------------------------
        // Z = K Q^T: wave owns s-rows w*16..+16, all 256 t
        float4v z[16];
        #pragma unroll
        for (int tt = 0; tt < 16; ++tt) z[tt] = fzero;
        #pragma unroll
        for (int ks = 0; ks < 2; ++ks) {
            short8v ak = *(const short8v*)(Ks + adr8(w * 16 + l15, ks * 32 + lq * 8));
            #pragma unroll
            for (int tt = 0; tt < 16; ++tt) {
                short8v bq = *(const short8v*)(Qs + adr8(tt * 16 + l15, ks * 32 + lq * 8));
                z[tt] = __builtin_amdgcn_mfma_f32_16x16x32_bf16(ak, bq, z[tt], 0, 0, 0);
            }
        }
        BAR();   // all QK^T reads done -> Qs/Ks regions may be overwritten (Wts)

        // softmax over t (query axis) for each of the lane's 4 s-rows
        float inv[4];
        #pragma unroll
        for (int r = 0; r < 4; ++r) {
            const int s = w * 16 + lq * 4 + r;
            float mm = -1e30f;
            #pragma unroll
            for (int tt = 0; tt < 16; ++tt) {
                int t = tt * 16 + l15;
                float v = (t >= s) ? z[tt][r] * SCALE : -1e30f;  // causal: keep t >= s
                z[tt][r] = v;
                mm = fmaxf(mm, v);
            }
            mm = fmaxf(mm, __shfl_xor(mm, 1));
            mm = fmaxf(mm, __shfl_xor(mm, 2));
            mm = fmaxf(mm, __shfl_xor(mm, 4));
            mm = fmaxf(mm, __shfl_xor(mm, 8));
            float ss = 0.f;
            #pragma unroll
            for (int tt = 0; tt < 16; ++tt) {
                float p = (z[tt][r] > -1e29f) ? __expf(z[tt][r] - mm) : 0.f;
                z[tt][r] = p;
                ss += p;
            }
            ss += __shfl_xor(ss, 1);
            ss += __shfl_xor(ss, 2);
            ss += __shfl_xor(ss, 4);
            ss += __shfl_xor(ss, 8);
            inv[r] = 1.f / ss;
        }

        // normalized weights -> Wts[t][s] (bf16, adr32)
        #pragma unroll
        for (int tt = 0; tt < 16; ++tt) {
            const int t = tt * 16 + l15;
            const int col = w * 16 + lq * 4;
            ushort4v pw;
            pw[0] = f2bf(z[tt][0] * inv[0]);
            pw[1] = f2bf(z[tt][1] * inv[1]);
            pw[2] = f2bf(z[tt][2] * inv[2]);
            pw[3] = f2bf(z[tt][3] * inv[3]);
            *(ushort4v*)(Wts + adr32(t, col)) = pw;
        }

        // cross-batch prefetch: z is dead -> load next batch's first two chunks
        if (bb == 0) {
            const float* Xb1 = X + (long)(b0 + 256) * TT * CE;
            issueA(Xb1, 0);
            issueB(Xb1, 64);
        }
        BAR();   // Wts visible

        // O = W V: wave owns t-rows w*16..+16, all 64 h
        float4v o[4];
        #pragma unroll
        for (int ht = 0; ht < 4; ++ht) o[ht] = fzero;
        #pragma unroll
        for (int ks = 0; ks < 8; ++ks) {
            short8v aw = *(const short8v*)(Wts + adr32(w * 16 + l15, ks * 32 + lq * 8));
            #pragma unroll
            for (int ht = 0; ht < 4; ++ht) {
                short8v bv = *(const short8v*)(Vts + adr32(ht * 16 + l15, ks * 32 + lq * 8));
                o[ht] = __builtin_amdgcn_mfma_f32_16x16x32_bf16(aw, bv, o[ht], 0, 0, 0);
            }
        }

        // store O (f32; 16 lanes write 64B contiguous per (t, ht))
        float* ob = out + (long)bat * TT * HD;
        #pragma unroll
        for (int ht = 0; ht < 4; ++ht)
            #pragma unroll
            for (int r = 0; r < 4; ++r)
                ob[(w * 16 + lq * 4 + r) * HD + ht * 16 + l15] = o[ht][r];

        if (bb == 0) BAR();   // PV LDS reads done before next batch's staging
    }
}

// ---------------------------------------------------------------------------
extern "C" void kernel_launch(void* const* d_in, const int* in_sizes, int n_in,
                              void* d_out, int out_size, void* d_ws, size_t ws_size,
                              hipStream_t stream) {
    const float* X  = (const float*)d_in[0];
    const float* Wk = (const float*)d_in[1];
    const float* Wq = (const float*)d_in[2];
    const float* Wv = (const float*)d_in[3];
    float* out = (float*)d_out;

    unsigned short* Wt = (unsigned short*)d_ws;   // 3*64*384 bf16 = 147456 B

    (void)hipFuncSetAttribute(reinterpret_cast<const void*>(fused),
                              hipFuncAttributeMaxDynamicSharedMemorySize, 163840);

    wprep<<<288, 256, 0, stream>>>(Wk, Wq, Wv, Wt);
    fused<<<256, 1024, 163840, stream>>>(X, Wt, out);
}

// Round 6
// 85.554 us; speedup vs baseline: 2.0115x; 2.0115x over previous
//
#include <hip/hip_runtime.h>
#include <hip/hip_bf16.h>

#define TT 256   // sequence length
#define CE 384   // embed
#define HD 64    // head size

typedef __attribute__((ext_vector_type(8))) short short8v;
typedef __attribute__((ext_vector_type(4))) float float4v;
typedef __attribute__((ext_vector_type(4))) unsigned int uint4v;
typedef __attribute__((ext_vector_type(4))) unsigned short ushort4v;

#define SCALE 0.05103103630798287f  // 384^-0.5 (reference scales by C, not H)

__device__ __forceinline__ unsigned short f2bf(float f) {
    union { __hip_bfloat16 b; unsigned short u; } cv;
    cv.b = __float2bfloat16(f);   // RNE; pairs fuse to v_cvt_pk_bf16_f32
    return cv.u;
}
__device__ __forceinline__ unsigned int pk2(float a, float b) {
    return (unsigned int)f2bf(a) | ((unsigned int)f2bf(b) << 16);
}

// Swizzled LDS addressing: rows of 64 bf16 (128 B), 16B-chunk XOR swizzle
__device__ __forceinline__ int adr8(int row, int col) {
    return row * 128 + ((((col >> 3) ^ (row & 7)) & 7) << 4) + ((col & 7) << 1);
}

// raw barrier: drain LDS ops only -- global prefetch loads stay in flight
#define BAR() do {                                            \
    asm volatile("s_waitcnt lgkmcnt(0)" ::: "memory");        \
    __builtin_amdgcn_s_barrier();                             \
    __builtin_amdgcn_sched_barrier(0);                        \
} while (0)

// ---------------- kernel 0: weight transpose + bf16 convert -----------------
__global__ void wprep(const float* __restrict__ Wk, const float* __restrict__ Wq,
                      const float* __restrict__ Wv, unsigned short* __restrict__ Wt) {
    int idx = blockIdx.x * 256 + threadIdx.x;
    if (idx >= 3 * HD * CE) return;
    int w = idx / (HD * CE);
    int rem = idx - w * (HD * CE);
    int h = rem / CE;
    int c = rem - h * CE;
    const float* W = (w == 0) ? Wk : (w == 1) ? Wq : Wv;
    Wt[idx] = f2bf(W[c * HD + h]);
}

// ---------------- kernel 1: QKV projection GEMM -----------------------------
// 512 threads (8 waves), tile = 128 t-rows x 192 n-cols, grid = 512 batches x 2.
// LDS 40 KiB -> 2 blocks/CU (with VGPR<=128 via launch_bounds(512,4)).
// Wave w owns rows w*16..+16, all 192 n. acc = 12 float4v = 48 AGPR.
__global__ __launch_bounds__(512, 4)
void qkv(const float* __restrict__ X, const unsigned short* __restrict__ Wt,
         unsigned short* __restrict__ Kb, unsigned short* __restrict__ Qb,
         unsigned short* __restrict__ Vt) {
    __shared__ char lds[40960];
    char* Xs = lds;            // 16 KiB: 128 rows x 64 bf16 (adr8)
    char* Ws = lds + 16384;    // 24 KiB: 192 rows x 64 bf16 (adr8)

    const int bid = blockIdx.x;
    const int b = bid >> 1, rh = bid & 1;       // batch, row-half
    const int tid = threadIdx.x;
    const int w = tid >> 6, l = tid & 63;
    const int l15 = l & 15, lq = l >> 4;

    const float* Xb = X + ((long)b * TT + rh * 128) * CE;

    // staging slots: X 1024 chunks/512thr = 2; W 1536/512 = 3
    const int xt0 = tid >> 3,        xk0 = tid & 7;
    const int xt1 = 64 + (tid >> 3), xk1 = tid & 7;
    const int wn0 = tid >> 3;
    const int wn1 = 64 + (tid >> 3);
    const int wn2 = 128 + (tid >> 3);
    const int wk = tid & 7;

    float4 xa0, xa1, xb0, xb1;
    uint4v wr0, wr1, wr2;

    auto issue = [&](int kk) {
        const float* s0 = Xb + xt0 * CE + kk + xk0 * 8;
        xa0 = *(const float4*)s0;  xa1 = *(const float4*)(s0 + 4);
        const float* s1 = Xb + xt1 * CE + kk + xk1 * 8;
        xb0 = *(const float4*)s1;  xb1 = *(const float4*)(s1 + 4);
        wr0 = *(const uint4v*)(Wt + wn0 * CE + kk + wk * 8);
        wr1 = *(const uint4v*)(Wt + wn1 * CE + kk + wk * 8);
        wr2 = *(const uint4v*)(Wt + wn2 * CE + kk + wk * 8);
    };
    auto store = [&]() {
        uint4v p0 = {pk2(xa0.x, xa0.y), pk2(xa0.z, xa0.w), pk2(xa1.x, xa1.y), pk2(xa1.z, xa1.w)};
        *(uint4v*)(Xs + xt0 * 128 + (((xk0 ^ (xt0 & 7)) & 7) << 4)) = p0;
        uint4v p1 = {pk2(xb0.x, xb0.y), pk2(xb0.z, xb0.w), pk2(xb1.x, xb1.y), pk2(xb1.z, xb1.w)};
        *(uint4v*)(Xs + xt1 * 128 + (((xk1 ^ (xt1 & 7)) & 7) << 4)) = p1;
        *(uint4v*)(Ws + wn0 * 128 + (((wk ^ (wn0 & 7)) & 7) << 4)) = wr0;
        *(uint4v*)(Ws + wn1 * 128 + (((wk ^ (wn1 & 7)) & 7) << 4)) = wr1;
        *(uint4v*)(Ws + wn2 * 128 + (((wk ^ (wn2 & 7)) & 7) << 4)) = wr2;
    };

    const float4v fzero = {0.f, 0.f, 0.f, 0.f};
    float4v acc[12];
    #pragma unroll
    for (int j = 0; j < 12; ++j) acc[j] = fzero;

    issue(0);
    for (int kc = 0; kc < 6; ++kc) {
        BAR();                         // prev MFMA LDS reads done
        store();
        if (kc < 5) issue((kc + 1) * 64);   // next chunk in flight across MFMA
        BAR();                         // ds_writes visible; globals stay in flight
        #pragma unroll
        for (int ks = 0; ks < 2; ++ks) {
            short8v a = *(const short8v*)(Xs + adr8(w * 16 + l15, ks * 32 + lq * 8));
            #pragma unroll
            for (int nt = 0; nt < 12; ++nt) {
                short8v bb = *(const short8v*)(Ws + adr8(nt * 16 + l15, ks * 32 + lq * 8));
                acc[nt] = __builtin_amdgcn_mfma_f32_16x16x32_bf16(a, bb, acc[nt], 0, 0, 0);
            }
        }
    }

    // epilogue: t = rh*128 + w*16 + lq*4 + r ; n = nt*16 + l15
    const int t0 = rh * 128 + w * 16 + lq * 4;
    #pragma unroll
    for (int nt = 0; nt < 12; ++nt) {
        const int n = nt * 16 + l15;
        if (n < 64) {              // K row-major [b][t][h]
            #pragma unroll
            for (int r = 0; r < 4; ++r)
                Kb[((long)b * TT + t0 + r) * HD + n] = f2bf(acc[nt][r]);
        } else if (n < 128) {      // Q row-major
            const int h = n - 64;
            #pragma unroll
            for (int r = 0; r < 4; ++r)
                Qb[((long)b * TT + t0 + r) * HD + h] = f2bf(acc[nt][r]);
        } else {                   // V transposed [b][h][t]
            const int h = n - 128;
            ushort4v pv;
            pv[0] = f2bf(acc[nt][0]);
            pv[1] = f2bf(acc[nt][1]);
            pv[2] = f2bf(acc[nt][2]);
            pv[3] = f2bf(acc[nt][3]);
            *(ushort4v*)(Vt + ((long)b * HD + h) * TT + t0) = pv;
        }
    }
}

// ---------------- kernel 2: attention (query-axis softmax) ------------------
// 512 threads (8 waves), one batch per block, 80 KiB LDS -> 2 blocks/CU.
// s processed in 4 slabs of 64. QK^T: wave (sw = w&3) owns 16 s-rows,
// (th = w>>2) owns t-half of 128 -> z[8]; softmax over t merges the two
// t-halves via an online (max,sum) exchange in LDS. PV: wave owns 32 t-rows.
__global__ __launch_bounds__(512, 4)
void attn(const unsigned short* __restrict__ Kb, const unsigned short* __restrict__ Qb,
          const unsigned short* __restrict__ Vt, float* __restrict__ out) {
    extern __shared__ char lds[];
    char* Qs  = lds;            // 32 KiB: 256 x 64 bf16 (adr8)
    char* Wts = lds + 32768;    // 32 KiB: 256 t-rows x 64 s-cols bf16 (adr8)
    char* Ks  = lds + 65536;    //  8 KiB: 64 x 64 bf16 (adr8); smx overlays
    char* Vts = lds + 73728;    //  8 KiB: 64 h-rows x 64 s-cols bf16 (adr8)
    float2* smx = (float2*)Ks;  // [2][64] (max,sum) -- valid only after QK^T

    const int b = blockIdx.x;
    const int tid = threadIdx.x;
    const int w = tid >> 6, l = tid & 63;
    const int l15 = l & 15, lq = l >> 4;
    const int sw = w & 3, th = w >> 2;

    // stage Q (256x64): 4 chunks/thread
    #pragma unroll
    for (int j = 0; j < 4; ++j) {
        int ci = j * 512 + tid;
        int t = ci >> 3, k8 = ci & 7;
        uint4v p = *(const uint4v*)(Qb + ((long)b * TT + t) * HD + k8 * 8);
        *(uint4v*)(Qs + t * 128 + (((k8 ^ (t & 7)) & 7) << 4)) = p;
    }

    const float4v fzero = {0.f, 0.f, 0.f, 0.f};
    float4v o[2][4];
    #pragma unroll
    for (int i = 0; i < 2; ++i)
        #pragma unroll
        for (int j = 0; j < 4; ++j) o[i][j] = fzero;

    const int vrow = tid >> 3, vc8 = tid & 7;   // slab staging: 512 chunks each

    for (int sb = 0; sb < 4; ++sb) {
        const int s0 = sb * 64;
        __syncthreads();   // prev PV reads done (and smx reads); Qs visible at sb=0
        // stage K slab [s0..s0+64][64] and V^T slab [64][s0..s0+64]
        {
            uint4v pk = *(const uint4v*)(Kb + ((long)b * TT + s0 + vrow) * HD + vc8 * 8);
            *(uint4v*)(Ks + vrow * 128 + (((vc8 ^ (vrow & 7)) & 7) << 4)) = pk;
            uint4v pv = *(const uint4v*)(Vt + ((long)b * HD + vrow) * TT + s0 + vc8 * 8);
            *(uint4v*)(Vts + vrow * 128 + (((vc8 ^ (vrow & 7)) & 7) << 4)) = pv;
        }
        __syncthreads();

        // Z = K Q^T : z[tt], t = th*128 + tt*16 + l15, s-row = sw*16 + lq*4 + r
        float4v z[8];
        #pragma unroll
        for (int tt = 0; tt < 8; ++tt) z[tt] = fzero;
        #pragma unroll
        for (int ks = 0; ks < 2; ++ks) {
            short8v ak = *(const short8v*)(Ks + adr8(sw * 16 + l15, ks * 32 + lq * 8));
            #pragma unroll
            for (int tt = 0; tt < 8; ++tt) {
                short8v bq = *(const short8v*)(Qs + adr8(th * 128 + tt * 16 + l15, ks * 32 + lq * 8));
                z[tt] = __builtin_amdgcn_mfma_f32_16x16x32_bf16(ak, bq, z[tt], 0, 0, 0);
            }
        }
        __syncthreads();   // all QK^T reads of Ks done -> smx overlay safe

        // local softmax partials over this wave's t-half
        float pm[4], fac[4];
        #pragma unroll
        for (int r = 0; r < 4; ++r) {
            const int s = s0 + sw * 16 + lq * 4 + r;
            float mm = -1e30f;
            #pragma unroll
            for (int tt = 0; tt < 8; ++tt) {
                int t = th * 128 + tt * 16 + l15;
                float v = (t >= s) ? z[tt][r] * SCALE : -1e30f;  // causal: keep t >= s
                z[tt][r] = v;
                mm = fmaxf(mm, v);
            }
            mm = fmaxf(mm, __shfl_xor(mm, 1));
            mm = fmaxf(mm, __shfl_xor(mm, 2));
            mm = fmaxf(mm, __shfl_xor(mm, 4));
            mm = fmaxf(mm, __shfl_xor(mm, 8));
            float ps = 0.f;
            #pragma unroll
            for (int tt = 0; tt < 8; ++tt) {
                float p = (z[tt][r] > -1e29f) ? __expf(z[tt][r] - mm) : 0.f;
                z[tt][r] = p;
                ps += p;
            }
            ps += __shfl_xor(ps, 1);
            ps += __shfl_xor(ps, 2);
            ps += __shfl_xor(ps, 4);
            ps += __shfl_xor(ps, 8);
            pm[r] = mm;
            if (l15 == 0) smx[th * 64 + sw * 16 + lq * 4 + r] = make_float2(mm, ps);
        }
        __syncthreads();   // partials visible

        // merge the two t-halves (online-softmax merge), then normalize factor
        #pragma unroll
        for (int r = 0; r < 4; ++r) {
            const int row = sw * 16 + lq * 4 + r;
            float2 h0 = smx[row];
            float2 h1 = smx[64 + row];
            float m = fmaxf(h0.x, h1.x);
            float denom = h0.y * __expf(h0.x - m) + h1.y * __expf(h1.x - m);
            fac[r] = __expf(pm[r] - m) / denom;
        }

        // normalized weights -> Wts[t][s_local] (bf16, adr8)
        #pragma unroll
        for (int tt = 0; tt < 8; ++tt) {
            const int t = th * 128 + tt * 16 + l15;
            const int col = sw * 16 + lq * 4;
            ushort4v pw;
            pw[0] = f2bf(z[tt][0] * fac[0]);
            pw[1] = f2bf(z[tt][1] * fac[1]);
            pw[2] = f2bf(z[tt][2] * fac[2]);
            pw[3] = f2bf(z[tt][3] * fac[3]);
            *(ushort4v*)(Wts + t * 128 + ((((col >> 3) ^ (t & 7)) & 7) << 4) + ((col & 7) << 1)) = pw;
        }
        __syncthreads();   // Wts visible

        // O += W V : wave owns t-rows w*32..+32, all 64 h; k = 64 slab cols
        #pragma unroll
        for (int ks = 0; ks < 2; ++ks) {
            short8v aw0 = *(const short8v*)(Wts + adr8(w * 32 + l15,      ks * 32 + lq * 8));
            short8v aw1 = *(const short8v*)(Wts + adr8(w * 32 + 16 + l15, ks * 32 + lq * 8));
            #pragma unroll
            for (int ht = 0; ht < 4; ++ht) {
                short8v bv = *(const short8v*)(Vts + adr8(ht * 16 + l15, ks * 32 + lq * 8));
                o[0][ht] = __builtin_amdgcn_mfma_f32_16x16x32_bf16(aw0, bv, o[0][ht], 0, 0, 0);
                o[1][ht] = __builtin_amdgcn_mfma_f32_16x16x32_bf16(aw1, bv, o[1][ht], 0, 0, 0);
            }
        }
    }

    // store O (f32, coalesced 64B per 16-lane group)
    #pragma unroll
    for (int rt = 0; rt < 2; ++rt)
        #pragma unroll
        for (int ht = 0; ht < 4; ++ht) {
            int t0 = w * 32 + rt * 16 + lq * 4;
            int h = ht * 16 + l15;
            #pragma unroll
            for (int r = 0; r < 4; ++r)
                out[((long)b * TT + t0 + r) * HD + h] = o[rt][ht][r];
        }
}

// ---------------------------------------------------------------------------
extern "C" void kernel_launch(void* const* d_in, const int* in_sizes, int n_in,
                              void* d_out, int out_size, void* d_ws, size_t ws_size,
                              hipStream_t stream) {
    const float* X  = (const float*)d_in[0];
    const float* Wk = (const float*)d_in[1];
    const float* Wq = (const float*)d_in[2];
    const float* Wv = (const float*)d_in[3];
    float* out = (float*)d_out;

    char* ws = (char*)d_ws;
    unsigned short* Wt = (unsigned short*)ws;                              // 147456 B
    unsigned short* Kb = (unsigned short*)(ws + 147456);                   // 16 MiB
    unsigned short* Qb = (unsigned short*)(ws + 147456 + 16777216L);       // 16 MiB
    unsigned short* Vt = (unsigned short*)(ws + 147456 + 2 * 16777216L);   // 16 MiB

    (void)hipFuncSetAttribute(reinterpret_cast<const void*>(attn),
                              hipFuncAttributeMaxDynamicSharedMemorySize, 81920);

    wprep<<<288, 256, 0, stream>>>(Wk, Wq, Wv, Wt);
    qkv<<<1024, 512, 0, stream>>>(X, Wt, Kb, Qb, Vt);
    attn<<<512, 512, 81920, stream>>>(Kb, Qb, Vt, out);
}